// Round 1
// baseline (30180.231 us; speedup 1.0000x reference)
//
#include <hip/hip_runtime.h>
#include <hip/hip_bf16.h>
#include <math.h>

// SequenceDiT forward, f32 correctness-first baseline.
// B=4 L=1024 H=1024 NH=16 HD=64 DEPTH=12 MLP=4096 D_ESM=1280 V=26
#define B_    4
#define L_    1024
#define H_    1024
#define NH_   16
#define HD_   64
#define DEPTH_ 12
#define MLPD_ 4096
#define DESM_ 1280
#define M_    (B_*L_)   // 4096 rows

#define EP_NONE  0
#define EP_GELU  1
#define EP_RESID 2

// ---------------- embedding features (t / L sinusoidal) ----------------
__global__ __launch_bounds__(512) void embed_kernel(const int* __restrict__ t,
                                                    const int* __restrict__ Tp,
                                                    const int* __restrict__ Lt,
                                                    float* __restrict__ tfeat,
                                                    float* __restrict__ lfeat)
{
    int tid = threadIdx.x;
    float T = (float)Tp[0];
    if (tid < 512) {                 // 4 * 128 items for t (T_FREQ=256, half=128)
        int b = tid >> 7, i = tid & 127;
        float tn = (float)t[b] / T;
        float f = expf(-9.210340371976184f * (float)i / 128.f);  // ln(10000)
        float arg = tn * f;
        tfeat[b*256 + i]       = cosf(arg);
        tfeat[b*256 + 128 + i] = sinf(arg);
    }
    if (tid < 256) {                 // 4 * 64 items for L (L_FREQ=128, half=64)
        int b = tid >> 6, i = tid & 63;
        float f = expf(-9.210340371976184f * (float)i / 64.f);
        float arg = (float)Lt[b] * f;
        lfeat[b*128 + i]      = cosf(arg);
        lfeat[b*128 + 64 + i] = sinf(arg);
    }
}

// ---------------- rope cos/sin table: [L][64] ----------------
__global__ __launch_bounds__(256) void rope_init_kernel(float* __restrict__ ct, float* __restrict__ st)
{
    int idx = blockIdx.x*256 + threadIdx.x;   // < 65536
    int l = idx >> 6, d = idx & 63;
    // inv_freq[i] = 10000^{-i/32}, angle index = d&31 (concat(freqs,freqs))
    float ang = (float)l * expf(-9.210340371976184f * (float)(d & 31) / 32.f);
    ct[idx] = cosf(ang);
    st[idx] = sinf(ang);
}

// ---------------- small GEMM: A[4,K] @ W[K,N] + bias ----------------
// mode 0: store; 1: silu store; 2: out += (acc+bias)
__global__ __launch_bounds__(256) void small_gemm(const float* __restrict__ A,
                                                  const float* __restrict__ W,
                                                  const float* __restrict__ bias,
                                                  float* __restrict__ out,
                                                  int K, int N, int mode)
{
    int idx = blockIdx.x*256 + threadIdx.x;
    if (idx >= 4*N) return;
    int b = idx / N, n = idx % N;
    float acc = bias[n];
    const float* a = A + (size_t)b*K;
    for (int k = 0; k < K; k++) acc = fmaf(a[k], W[(size_t)k*N + n], acc);
    if (mode == 1) acc = acc / (1.f + expf(-acc));
    if (mode == 2) out[idx] += acc; else out[idx] = acc;
}

__global__ __launch_bounds__(256) void silu_kernel(const float* __restrict__ in,
                                                   float* __restrict__ out, int n)
{
    int i = blockIdx.x*256 + threadIdx.x;
    if (i < n) { float v = in[i]; out[i] = v / (1.f + expf(-v)); }
}

// ---------------- LayerNorm + modulate ----------------
// out[row,:] = ln(x[row,:]) * (1 + sc[b,:]) + sh[b,:]
__global__ __launch_bounds__(256) void ln_mod_kernel(const float* __restrict__ x,
                                                     float* __restrict__ out,
                                                     const float* __restrict__ modbuf,
                                                     int mstride, int sh_off, int sc_off)
{
    int row = blockIdx.x;          // 0..4095
    int b = row >> 10;             // row / L
    int tid = threadIdx.x;
    const float4* xr = (const float4*)(x + (size_t)row*H_);
    float4 v = xr[tid];
    float s  = v.x + v.y + v.z + v.w;
    float sq = v.x*v.x + v.y*v.y + v.z*v.z + v.w*v.w;
    #pragma unroll
    for (int off = 1; off < 64; off <<= 1) {
        s  += __shfl_xor(s, off);
        sq += __shfl_xor(sq, off);
    }
    __shared__ float ls[4], lsq[4];
    int wid = tid >> 6;
    if ((tid & 63) == 0) { ls[wid] = s; lsq[wid] = sq; }
    __syncthreads();
    s  = ls[0] + ls[1] + ls[2] + ls[3];
    sq = lsq[0] + lsq[1] + lsq[2] + lsq[3];
    float mu  = s * (1.f/(float)H_);
    float var = sq * (1.f/(float)H_) - mu*mu;
    float rs  = rsqrtf(var + 1e-6f);
    const float* sh = modbuf + (size_t)b*mstride + sh_off;
    const float* sc = modbuf + (size_t)b*mstride + sc_off;
    int c = tid << 2;
    float4 o;
    o.x = (v.x - mu)*rs*(1.f + sc[c+0]) + sh[c+0];
    o.y = (v.y - mu)*rs*(1.f + sc[c+1]) + sh[c+1];
    o.z = (v.z - mu)*rs*(1.f + sc[c+2]) + sh[c+2];
    o.w = (v.w - mu)*rs*(1.f + sc[c+3]) + sh[c+3];
    ((float4*)(out + (size_t)row*H_))[tid] = o;
}

// ---------------- RoPE on q and k in qkv buffer ----------------
__global__ __launch_bounds__(256) void rope_kernel(float* __restrict__ qkv,
                                                   const float* __restrict__ ct,
                                                   const float* __restrict__ st)
{
    int idx = blockIdx.x*256 + threadIdx.x;   // < 4*1024*16*32
    int p  = idx & 31;          // pair index
    int hh = (idx >> 5) & 15;   // head
    int l  = (idx >> 9) & 1023;
    int b  = idx >> 19;
    int d0 = p*2;
    float c0 = ct[l*64 + d0],   s0 = st[l*64 + d0];
    float c1 = ct[l*64 + d0+1], s1 = st[l*64 + d0+1];
    size_t base = ((size_t)(b*L_ + l))*(3*H_) + hh*HD_;
    // q
    float2* qp = (float2*)(qkv + base + d0);
    float2 v = *qp;
    float2 r;
    r.x = v.x*c0 - v.y*s0;   // out[2i]   = x[2i]*cos - x[2i+1]*sin
    r.y = v.y*c1 + v.x*s1;   // out[2i+1] = x[2i+1]*cos + x[2i]*sin
    *qp = r;
    // k
    float2* kp = (float2*)(qkv + base + H_ + d0);
    v = *kp;
    r.x = v.x*c0 - v.y*s0;
    r.y = v.y*c1 + v.x*s1;
    *kp = r;
}

// ---------------- tiled f32 GEMM: C[M,N] = A[M,K] @ W[K,N] + bias ----------------
// ep: EP_NONE store; EP_GELU gelu-tanh store; EP_RESID out += gate[b,n]*(acc+bias)
__global__ __launch_bounds__(256) void gemm_kernel(const float* __restrict__ A,
                                                   const float* __restrict__ W,
                                                   const float* __restrict__ bias,
                                                   float* __restrict__ out,
                                                   int M, int N, int K, int ep,
                                                   const float* __restrict__ gate,
                                                   int gstride, int goff)
{
    __shared__ float As[16][68];   // pad 4 keeps float4 alignment, 2-way banks (free)
    __shared__ float Bs[16][68];
    int tid = threadIdx.x;
    int tx = tid & 15, ty = tid >> 4;
    int m0 = blockIdx.y << 6, n0 = blockIdx.x << 6;
    float acc[4][4] = {};
    for (int k0 = 0; k0 < K; k0 += 16) {
        #pragma unroll
        for (int i = 0; i < 4; i++) {
            int idx = (i << 8) + tid;       // 0..1023
            int r = idx >> 4, c = idx & 15; // 64 rows x 16 cols of A
            As[c][r] = A[(size_t)(m0 + r)*K + (k0 + c)];
        }
        #pragma unroll
        for (int i = 0; i < 4; i++) {
            int idx = (i << 8) + tid;
            int r = idx >> 6, c = idx & 63; // 16 rows x 64 cols of W
            int n = n0 + c;
            Bs[r][c] = (n < N) ? W[(size_t)(k0 + r)*N + n] : 0.f;
        }
        __syncthreads();
        #pragma unroll
        for (int kk = 0; kk < 16; kk++) {
            float4 a = *(const float4*)&As[kk][ty << 2];
            float4 b = *(const float4*)&Bs[kk][tx << 2];
            float av[4] = {a.x, a.y, a.z, a.w};
            float bv[4] = {b.x, b.y, b.z, b.w};
            #pragma unroll
            for (int i = 0; i < 4; i++)
                #pragma unroll
                for (int j = 0; j < 4; j++)
                    acc[i][j] = fmaf(av[i], bv[j], acc[i][j]);
        }
        __syncthreads();
    }
    #pragma unroll
    for (int i = 0; i < 4; i++) {
        int row = m0 + (ty << 2) + i;
        int bb = row >> 10;
        #pragma unroll
        for (int j = 0; j < 4; j++) {
            int n = n0 + (tx << 2) + j;
            if (n >= N) continue;
            float v = acc[i][j] + bias[n];
            size_t oi = (size_t)row*N + n;
            if (ep == EP_GELU) {
                float u = v;
                out[oi] = 0.5f*u*(1.f + tanhf(0.7978845608028654f*(u + 0.044715f*u*u*u)));
            } else if (ep == EP_RESID) {
                out[oi] += gate[(size_t)bb*gstride + goff + n] * v;
            } else {
                out[oi] = v;
            }
        }
    }
}

// ---------------- flash attention, 64 q-rows per block ----------------
// grid (L/64, NH, B), block 256. qkv row layout: [q(1024) | k(1024) | v(1024)],
// per-head slice h*64. out[b,l,h*64+d].
__global__ __launch_bounds__(256) void attn_kernel(const float* __restrict__ qkv,
                                                   float* __restrict__ out)
{
    __shared__ float Qs[64][68];
    __shared__ float KV[64][68];   // holds K tile, then V^T tile
    __shared__ float S[64][68];
    __shared__ float mrow[64], lrow[64], arow[64];
    int tid = threadIdx.x;
    int tx = tid & 15, ty = tid >> 4;
    int l0 = blockIdx.x << 6;
    int h  = blockIdx.y;
    int b  = blockIdx.z;
    const float* base = qkv + (size_t)b*L_*(3*H_) + h*HD_;
    #pragma unroll
    for (int i = 0; i < 16; i++) {
        int idx = (i << 8) + tid;
        int r = idx >> 6, c = idx & 63;
        Qs[r][c] = base[(size_t)(l0 + r)*(3*H_) + c];
    }
    if (tid < 64) { mrow[tid] = -1e30f; lrow[tid] = 0.f; }
    float o[4][4] = {};
    __syncthreads();
    for (int kt = 0; kt < 16; kt++) {
        int k0 = kt << 6;
        // K tile
        #pragma unroll
        for (int i = 0; i < 16; i++) {
            int idx = (i << 8) + tid;
            int r = idx >> 6, c = idx & 63;
            KV[r][c] = base[(size_t)(k0 + r)*(3*H_) + H_ + c];
        }
        __syncthreads();
        // S = 0.125 * Q K^T  (rows ty*4+i, cols tx+16*j)
        float s[4][4] = {};
        for (int k = 0; k < 64; k += 4) {
            float4 aa[4], bb[4];
            #pragma unroll
            for (int i = 0; i < 4; i++) aa[i] = *(const float4*)&Qs[(ty<<2)+i][k];
            #pragma unroll
            for (int j = 0; j < 4; j++) bb[j] = *(const float4*)&KV[tx + (j<<4)][k];
            #pragma unroll
            for (int i = 0; i < 4; i++)
                #pragma unroll
                for (int j = 0; j < 4; j++) {
                    s[i][j] = fmaf(aa[i].x, bb[j].x, s[i][j]);
                    s[i][j] = fmaf(aa[i].y, bb[j].y, s[i][j]);
                    s[i][j] = fmaf(aa[i].z, bb[j].z, s[i][j]);
                    s[i][j] = fmaf(aa[i].w, bb[j].w, s[i][j]);
                }
        }
        #pragma unroll
        for (int i = 0; i < 4; i++)
            #pragma unroll
            for (int j = 0; j < 4; j++)
                S[(ty<<2)+i][tx + (j<<4)] = s[i][j] * 0.125f;
        __syncthreads();
        // row max -> alpha (staggered column order: 2-way banks)
        if (tid < 64) {
            int r = tid;
            float mx = mrow[r];
            for (int k = 0; k < 64; k++) mx = fmaxf(mx, S[r][(k + r) & 63]);
            arow[r] = __expf(mrow[r] - mx);
            mrow[r] = mx;
        }
        __syncthreads();
        // P = exp(S - m)
        #pragma unroll
        for (int i = 0; i < 4; i++) {
            float mm = mrow[(ty<<2)+i];
            #pragma unroll
            for (int j = 0; j < 4; j++) {
                int cc = tx + (j<<4);
                S[(ty<<2)+i][cc] = __expf(S[(ty<<2)+i][cc] - mm);
            }
        }
        __syncthreads();
        // V^T tile (overwrites K) while one wave does row sums of P
        #pragma unroll
        for (int i = 0; i < 16; i++) {
            int idx = (i << 8) + tid;
            int r = idx >> 6, c = idx & 63;
            KV[c][r] = base[(size_t)(k0 + r)*(3*H_) + 2*H_ + c];
        }
        if (tid < 64) {
            int r = tid;
            float sm = 0.f;
            for (int k = 0; k < 64; k++) sm += S[r][(k + r) & 63];
            lrow[r] = lrow[r]*arow[r] + sm;
        }
        __syncthreads();
        // O = O*alpha + P @ V   (out cols tx+16*j via V^T rows)
        #pragma unroll
        for (int i = 0; i < 4; i++) {
            float al = arow[(ty<<2)+i];
            #pragma unroll
            for (int j = 0; j < 4; j++) o[i][j] *= al;
        }
        for (int k = 0; k < 64; k += 4) {
            float4 pp[4], vv[4];
            #pragma unroll
            for (int i = 0; i < 4; i++) pp[i] = *(const float4*)&S[(ty<<2)+i][k];
            #pragma unroll
            for (int j = 0; j < 4; j++) vv[j] = *(const float4*)&KV[tx + (j<<4)][k];
            #pragma unroll
            for (int i = 0; i < 4; i++)
                #pragma unroll
                for (int j = 0; j < 4; j++) {
                    o[i][j] = fmaf(pp[i].x, vv[j].x, o[i][j]);
                    o[i][j] = fmaf(pp[i].y, vv[j].y, o[i][j]);
                    o[i][j] = fmaf(pp[i].z, vv[j].z, o[i][j]);
                    o[i][j] = fmaf(pp[i].w, vv[j].w, o[i][j]);
                }
        }
        __syncthreads();
    }
    #pragma unroll
    for (int i = 0; i < 4; i++) {
        int r = (ty << 2) + i;
        float inv = 1.f / lrow[r];
        #pragma unroll
        for (int j = 0; j < 4; j++)
            out[((size_t)(b*L_ + l0 + r))*H_ + h*HD_ + tx + (j<<4)] = o[i][j] * inv;
    }
}

// ---------------- launcher ----------------
extern "C" void kernel_launch(void* const* d_in, const int* in_sizes, int n_in,
                              void* d_out, int out_size, void* d_ws, size_t ws_size,
                              hipStream_t stream)
{
    (void)in_sizes; (void)n_in; (void)out_size; (void)ws_size;
    const float* x_tokens  = (const float*)d_in[0];
    const int*   Ltgt      = (const int*)d_in[1];
    const int*   tarr      = (const int*)d_in[2];
    const int*   Tp        = (const int*)d_in[3];
    const float* proj_in_w = (const float*)d_in[4];
    const float* proj_in_b = (const float*)d_in[5];
    const float* t_w1 = (const float*)d_in[6];
    const float* t_b1 = (const float*)d_in[7];
    const float* t_w2 = (const float*)d_in[8];
    const float* t_b2 = (const float*)d_in[9];
    const float* l_w1 = (const float*)d_in[10];
    const float* l_b1 = (const float*)d_in[11];
    const float* l_w2 = (const float*)d_in[12];
    const float* l_b2 = (const float*)d_in[13];
    const float* qkv_w   = (const float*)d_in[14];
    const float* qkv_b   = (const float*)d_in[15];
    const float* aproj_w = (const float*)d_in[16];
    const float* aproj_b = (const float*)d_in[17];
    const float* mlp_w1  = (const float*)d_in[18];
    const float* mlp_b1  = (const float*)d_in[19];
    const float* mlp_w2  = (const float*)d_in[20];
    const float* mlp_b2  = (const float*)d_in[21];
    const float* ada_w   = (const float*)d_in[22];
    const float* ada_b   = (const float*)d_in[23];
    const float* fin_ada_w = (const float*)d_in[24];
    const float* fin_ada_b = (const float*)d_in[25];
    const float* fin_w   = (const float*)d_in[26];
    const float* fin_b   = (const float*)d_in[27];
    float* outp = (float*)d_out;

    float* ws = (float*)d_ws;
    float* x     = ws;  ws += (size_t)M_*H_;        // 4096x1024
    float* hbuf  = ws;  ws += (size_t)M_*H_;        // h / attn_out / h2
    float* qkvb  = ws;  ws += (size_t)M_*3*H_;      // 4096x3072
    float* mid   = ws;  ws += (size_t)M_*MLPD_;     // 4096x4096
    float* mods  = ws;  ws += B_*6*H_;              // adaLN mods (current layer)
    float* cvec  = ws;  ws += B_*H_;
    float* csil  = ws;  ws += B_*H_;
    float* tfeat = ws;  ws += B_*256;
    float* lfeat = ws;  ws += B_*128;
    float* thid  = ws;  ws += B_*H_;
    float* lhid  = ws;  ws += B_*H_;
    float* fmods = ws;  ws += B_*2*H_;
    float* ctab  = ws;  ws += L_*HD_;
    float* stab  = ws;  ws += L_*HD_;

    // conditioning path
    embed_kernel<<<1, 512, 0, stream>>>(tarr, Tp, Ltgt, tfeat, lfeat);
    rope_init_kernel<<<(L_*HD_)/256, 256, 0, stream>>>(ctab, stab);
    small_gemm<<<(B_*H_+255)/256, 256, 0, stream>>>(tfeat, t_w1, t_b1, thid, 256, H_, 1);
    small_gemm<<<(B_*H_+255)/256, 256, 0, stream>>>(lfeat, l_w1, l_b1, lhid, 128, H_, 1);
    small_gemm<<<(B_*H_+255)/256, 256, 0, stream>>>(thid, t_w2, t_b2, cvec, H_, H_, 0);
    small_gemm<<<(B_*H_+255)/256, 256, 0, stream>>>(lhid, l_w2, l_b2, cvec, H_, H_, 2);
    silu_kernel<<<(B_*H_+255)/256, 256, 0, stream>>>(cvec, csil, B_*H_);

    // x = x_tokens @ proj_in_w + b
    gemm_kernel<<<dim3(H_/64, M_/64), 256, 0, stream>>>(x_tokens, proj_in_w, proj_in_b, x,
                                                        M_, H_, DESM_, EP_NONE, nullptr, 0, 0);
    for (int l = 0; l < DEPTH_; l++) {
        small_gemm<<<(B_*6*H_+255)/256, 256, 0, stream>>>(csil, ada_w + (size_t)l*H_*6*H_,
                                                          ada_b + (size_t)l*6*H_, mods, H_, 6*H_, 0);
        ln_mod_kernel<<<M_, 256, 0, stream>>>(x, hbuf, mods, 6*H_, 0, H_);
        gemm_kernel<<<dim3(3*H_/64, M_/64), 256, 0, stream>>>(hbuf, qkv_w + (size_t)l*H_*3*H_,
                                                              qkv_b + (size_t)l*3*H_, qkvb,
                                                              M_, 3*H_, H_, EP_NONE, nullptr, 0, 0);
        rope_kernel<<<(B_*L_*NH_*32)/256, 256, 0, stream>>>(qkvb, ctab, stab);
        attn_kernel<<<dim3(L_/64, NH_, B_), 256, 0, stream>>>(qkvb, hbuf);
        gemm_kernel<<<dim3(H_/64, M_/64), 256, 0, stream>>>(hbuf, aproj_w + (size_t)l*H_*H_,
                                                            aproj_b + (size_t)l*H_, x,
                                                            M_, H_, H_, EP_RESID, mods, 6*H_, 2*H_);
        ln_mod_kernel<<<M_, 256, 0, stream>>>(x, hbuf, mods, 6*H_, 3*H_, 4*H_);
        gemm_kernel<<<dim3(MLPD_/64, M_/64), 256, 0, stream>>>(hbuf, mlp_w1 + (size_t)l*H_*MLPD_,
                                                               mlp_b1 + (size_t)l*MLPD_, mid,
                                                               M_, MLPD_, H_, EP_GELU, nullptr, 0, 0);
        gemm_kernel<<<dim3(H_/64, M_/64), 256, 0, stream>>>(mid, mlp_w2 + (size_t)l*MLPD_*H_,
                                                            mlp_b2 + (size_t)l*H_, x,
                                                            M_, H_, MLPD_, EP_RESID, mods, 6*H_, 5*H_);
    }
    // final head
    small_gemm<<<(B_*2*H_+255)/256, 256, 0, stream>>>(csil, fin_ada_w, fin_ada_b, fmods, H_, 2*H_, 0);
    ln_mod_kernel<<<M_, 256, 0, stream>>>(x, hbuf, fmods, 2*H_, 0, H_);
    gemm_kernel<<<dim3(1, M_/64), 256, 0, stream>>>(hbuf, fin_w, fin_b, outp,
                                                    M_, 26, H_, EP_NONE, nullptr, 0, 0);
}

// Round 2
// 13482.635 us; speedup vs baseline: 2.2385x; 2.2385x over previous
//
#include <hip/hip_runtime.h>
#include <hip/hip_bf16.h>
#include <math.h>

// SequenceDiT forward. Round 2: bf16 MFMA GEMMs (m97 structure), f32 attention.
// B=4 L=1024 H=1024 NH=16 HD=64 DEPTH=12 MLP=4096 D_ESM=1280 V=26
#define B_    4
#define L_    1024
#define H_    1024
#define NH_   16
#define HD_   64
#define DEPTH_ 12
#define MLPD_ 4096
#define DESM_ 1280
#define M_    (B_*L_)   // 4096 rows

typedef __bf16 bf16x8 __attribute__((ext_vector_type(8)));
typedef float  f32x4  __attribute__((ext_vector_type(4)));
typedef __hip_bfloat16 bf16;

// ---------------- embedding features (t / L sinusoidal) ----------------
__global__ __launch_bounds__(512) void embed_kernel(const int* __restrict__ t,
                                                    const int* __restrict__ Tp,
                                                    const int* __restrict__ Lt,
                                                    float* __restrict__ tfeat,
                                                    float* __restrict__ lfeat)
{
    int tid = threadIdx.x;
    float T = (float)Tp[0];
    if (tid < 512) {                 // 4 * 128 items for t (T_FREQ=256, half=128)
        int b = tid >> 7, i = tid & 127;
        float tn = (float)t[b] / T;
        float f = expf(-9.210340371976184f * (float)i / 128.f);  // ln(10000)
        float arg = tn * f;
        tfeat[b*256 + i]       = cosf(arg);
        tfeat[b*256 + 128 + i] = sinf(arg);
    }
    if (tid < 256) {                 // 4 * 64 items for L (L_FREQ=128, half=64)
        int b = tid >> 6, i = tid & 63;
        float f = expf(-9.210340371976184f * (float)i / 64.f);
        float arg = (float)Lt[b] * f;
        lfeat[b*128 + i]      = cosf(arg);
        lfeat[b*128 + 64 + i] = sinf(arg);
    }
}

// ---------------- rope cos/sin table: [L][64] ----------------
__global__ __launch_bounds__(256) void rope_init_kernel(float* __restrict__ ct, float* __restrict__ st)
{
    int idx = blockIdx.x*256 + threadIdx.x;   // < 65536
    int l = idx >> 6, d = idx & 63;
    float ang = (float)l * expf(-9.210340371976184f * (float)(d & 31) / 32.f);
    ct[idx] = cosf(ang);
    st[idx] = sinf(ang);
}

// ---------------- small GEMM: A[4,K] @ W[K,N] + bias ----------------
// mode 0: store; 1: silu store; 2: out += (acc+bias)
__global__ __launch_bounds__(256) void small_gemm(const float* __restrict__ A,
                                                  const float* __restrict__ W,
                                                  const float* __restrict__ bias,
                                                  float* __restrict__ out,
                                                  int K, int N, int mode)
{
    int idx = blockIdx.x*256 + threadIdx.x;
    if (idx >= 4*N) return;
    int b = idx / N, n = idx % N;
    float acc = bias[n];
    const float* a = A + (size_t)b*K;
    for (int k = 0; k < K; k++) acc = fmaf(a[k], W[(size_t)k*N + n], acc);
    if (mode == 1) acc = acc / (1.f + expf(-acc));
    if (mode == 2) out[idx] += acc; else out[idx] = acc;
}

__global__ __launch_bounds__(256) void silu_kernel(const float* __restrict__ in,
                                                   float* __restrict__ out, int n)
{
    int i = blockIdx.x*256 + threadIdx.x;
    if (i < n) { float v = in[i]; out[i] = v / (1.f + expf(-v)); }
}

// ---------------- f32 -> bf16 elementwise ----------------
__global__ __launch_bounds__(256) void f2b_kernel(const float* __restrict__ in,
                                                  bf16* __restrict__ out, int n)
{
    int i = blockIdx.x*256 + threadIdx.x;
    if (i < n) out[i] = __float2bfloat16(in[i]);
}

// ---------------- weight convert+transpose: W f32 [K][N] -> Wt bf16 [N][K] ----------------
__global__ __launch_bounds__(256) void wtrans_kernel(const float* __restrict__ W,
                                                     bf16* __restrict__ Wt,
                                                     int K, int N)
{
    __shared__ float t[32][33];
    int k0 = blockIdx.y << 5, n0 = blockIdx.x << 5;
    int tid = threadIdx.x;
    #pragma unroll
    for (int i = 0; i < 4; i++) {
        int idx = i*256 + tid;
        int r = idx >> 5, c = idx & 31;
        t[r][c] = W[(size_t)(k0 + r)*N + n0 + c];
    }
    __syncthreads();
    #pragma unroll
    for (int i = 0; i < 4; i++) {
        int idx = i*256 + tid;
        int r = idx >> 5, c = idx & 31;
        Wt[(size_t)(n0 + r)*K + k0 + c] = __float2bfloat16(t[c][r]);
    }
}

// ---------------- LayerNorm + modulate ----------------
template<bool BF16OUT>
__global__ __launch_bounds__(256) void ln_mod_kernel(const float* __restrict__ x,
                                                     void* __restrict__ out,
                                                     const float* __restrict__ modbuf,
                                                     int mstride, int sh_off, int sc_off)
{
    int row = blockIdx.x;          // 0..4095
    int b = row >> 10;
    int tid = threadIdx.x;
    const float4* xr = (const float4*)(x + (size_t)row*H_);
    float4 v = xr[tid];
    float s  = v.x + v.y + v.z + v.w;
    float sq = v.x*v.x + v.y*v.y + v.z*v.z + v.w*v.w;
    #pragma unroll
    for (int off = 1; off < 64; off <<= 1) {
        s  += __shfl_xor(s, off);
        sq += __shfl_xor(sq, off);
    }
    __shared__ float ls[4], lsq[4];
    int wid = tid >> 6;
    if ((tid & 63) == 0) { ls[wid] = s; lsq[wid] = sq; }
    __syncthreads();
    s  = ls[0] + ls[1] + ls[2] + ls[3];
    sq = lsq[0] + lsq[1] + lsq[2] + lsq[3];
    float mu  = s * (1.f/(float)H_);
    float var = sq * (1.f/(float)H_) - mu*mu;
    float rs  = rsqrtf(var + 1e-6f);
    const float* sh = modbuf + (size_t)b*mstride + sh_off;
    const float* sc = modbuf + (size_t)b*mstride + sc_off;
    int c = tid << 2;
    float o0 = (v.x - mu)*rs*(1.f + sc[c+0]) + sh[c+0];
    float o1 = (v.y - mu)*rs*(1.f + sc[c+1]) + sh[c+1];
    float o2 = (v.z - mu)*rs*(1.f + sc[c+2]) + sh[c+2];
    float o3 = (v.w - mu)*rs*(1.f + sc[c+3]) + sh[c+3];
    if (BF16OUT) {
        union { bf16 h[4]; uint2 u; } pk;
        pk.h[0] = __float2bfloat16(o0); pk.h[1] = __float2bfloat16(o1);
        pk.h[2] = __float2bfloat16(o2); pk.h[3] = __float2bfloat16(o3);
        ((uint2*)out)[(size_t)row*(H_/4) + tid] = pk.u;
    } else {
        float4 o; o.x = o0; o.y = o1; o.z = o2; o.w = o3;
        ((float4*)((float*)out + (size_t)row*H_))[tid] = o;
    }
}

// ---------------- RoPE on q and k in qkv buffer (f32) ----------------
__global__ __launch_bounds__(256) void rope_kernel(float* __restrict__ qkv,
                                                   const float* __restrict__ ct,
                                                   const float* __restrict__ st)
{
    int idx = blockIdx.x*256 + threadIdx.x;   // < 4*1024*16*32
    int p  = idx & 31;
    int hh = (idx >> 5) & 15;
    int l  = (idx >> 9) & 1023;
    int b  = idx >> 19;
    int d0 = p*2;
    float c0 = ct[l*64 + d0],   s0 = st[l*64 + d0];
    float c1 = ct[l*64 + d0+1], s1 = st[l*64 + d0+1];
    size_t base = ((size_t)(b*L_ + l))*(3*H_) + hh*HD_;
    float2* qp = (float2*)(qkv + base + d0);
    float2 v = *qp;
    float2 r;
    r.x = v.x*c0 - v.y*s0;
    r.y = v.y*c1 + v.x*s1;
    *qp = r;
    float2* kp = (float2*)(qkv + base + H_ + d0);
    v = *kp;
    r.x = v.x*c0 - v.y*s0;
    r.y = v.y*c1 + v.x*s1;
    *kp = r;
}

// ---------------- bf16 MFMA GEMM: C[M,N] = A[M,K] @ Bt[N,K]^T + bias ----------------
// m97 structure: 128x128 tile, BK=64, global_load_lds width-16 staging,
// XOR-swizzled LDS chunks (kc ^= row&7) so frag ds_read_b128 is 2-way-bank only.
// EP: 0 = store f32; 1 = gelu-tanh -> bf16; 2 = out_f32 += gate*(acc+bias); 3 = store bf16
template<int EP>
__global__ __launch_bounds__(256) void gemm_bf16(const bf16* __restrict__ A,
                                                 const bf16* __restrict__ Bt,
                                                 const float* __restrict__ bias,
                                                 void* __restrict__ outv,
                                                 int M, int N, int K,
                                                 const float* __restrict__ gate,
                                                 int gstride, int goff)
{
    __shared__ __align__(16) bf16 As[128*64];
    __shared__ __align__(16) bf16 Bs[128*64];
    int tid  = threadIdx.x;
    int lane = tid & 63, wave = tid >> 6;
    int wr = (wave >> 1) << 6;       // wave row origin in tile
    int wc = (wave & 1) << 6;        // wave col origin in tile
    int m0 = blockIdx.y << 7, n0 = blockIdx.x << 7;
    int ml = lane & 15, quad = lane >> 4;
    f32x4 acc[4][4] = {};

    const bf16* Abase = A  + (size_t)m0 * K;
    const bf16* Bbase = Bt + (size_t)n0 * K;

    for (int k0 = 0; k0 < K; k0 += 64) {
        // stage A tile: 128 rows x 64 k, 1024 16B-chunks, 4 per thread
        #pragma unroll
        for (int it = 0; it < 4; it++) {
            int p = it*256 + tid;
            int row = p >> 3;
            int kc  = (p & 7) ^ (row & 7);   // inverse swizzle on the global side
            __builtin_amdgcn_global_load_lds(
                (const __attribute__((address_space(1))) void*)(Abase + (size_t)row*K + k0 + kc*8),
                (__attribute__((address_space(3))) void*)(As + p*8), 16, 0, 0);
        }
        #pragma unroll
        for (int it = 0; it < 4; it++) {
            int p = it*256 + tid;
            int row = p >> 3;
            int kc  = (p & 7) ^ (row & 7);
            __builtin_amdgcn_global_load_lds(
                (const __attribute__((address_space(1))) void*)(Bbase + (size_t)row*K + k0 + kc*8),
                (__attribute__((address_space(3))) void*)(Bs + p*8), 16, 0, 0);
        }
        __syncthreads();   // drains vmcnt then barrier
        #pragma unroll
        for (int ks = 0; ks < 2; ks++) {
            int kq = ks*4 + quad;
            bf16x8 af[4], bfr[4];
            #pragma unroll
            for (int i = 0; i < 4; i++) {
                int m = wr + i*16 + ml;
                af[i] = *(const bf16x8*)(As + m*64 + ((kq ^ (m & 7)) << 3));
            }
            #pragma unroll
            for (int j = 0; j < 4; j++) {
                int n = wc + j*16 + ml;
                bfr[j] = *(const bf16x8*)(Bs + n*64 + ((kq ^ (n & 7)) << 3));
            }
            #pragma unroll
            for (int i = 0; i < 4; i++)
                #pragma unroll
                for (int j = 0; j < 4; j++)
                    acc[i][j] = __builtin_amdgcn_mfma_f32_16x16x32_bf16(af[i], bfr[j], acc[i][j], 0, 0, 0);
        }
        __syncthreads();
    }

    // epilogue: C/D layout col=lane&15, row=quad*4+reg (m89-verified)
    #pragma unroll
    for (int i = 0; i < 4; i++) {
        #pragma unroll
        for (int j = 0; j < 4; j++) {
            int col = n0 + wc + j*16 + ml;
            float bi = bias[col];
            #pragma unroll
            for (int r = 0; r < 4; r++) {
                int row = m0 + wr + i*16 + quad*4 + r;
                float v = acc[i][j][r] + bi;
                size_t oi = (size_t)row * N + col;
                if (EP == 0) {
                    ((float*)outv)[oi] = v;
                } else if (EP == 1) {
                    float g = 0.5f*v*(1.f + tanhf(0.7978845608028654f*(v + 0.044715f*v*v*v)));
                    ((bf16*)outv)[oi] = __float2bfloat16(g);
                } else if (EP == 2) {
                    int bb = row >> 10;
                    ((float*)outv)[oi] += gate[(size_t)bb*gstride + goff + col] * v;
                } else {
                    ((bf16*)outv)[oi] = __float2bfloat16(v);
                }
            }
        }
    }
}

// ---------------- f32 GEMM (final head only, N=26) ----------------
__global__ __launch_bounds__(256) void gemm_kernel(const float* __restrict__ A,
                                                   const float* __restrict__ W,
                                                   const float* __restrict__ bias,
                                                   float* __restrict__ out,
                                                   int M, int N, int K)
{
    __shared__ float As[16][68];
    __shared__ float Bs[16][68];
    int tid = threadIdx.x;
    int tx = tid & 15, ty = tid >> 4;
    int m0 = blockIdx.y << 6, n0 = blockIdx.x << 6;
    float acc[4][4] = {};
    for (int k0 = 0; k0 < K; k0 += 16) {
        #pragma unroll
        for (int i = 0; i < 4; i++) {
            int idx = (i << 8) + tid;
            int r = idx >> 4, c = idx & 15;
            As[c][r] = A[(size_t)(m0 + r)*K + (k0 + c)];
        }
        #pragma unroll
        for (int i = 0; i < 4; i++) {
            int idx = (i << 8) + tid;
            int r = idx >> 6, c = idx & 63;
            int n = n0 + c;
            Bs[r][c] = (n < N) ? W[(size_t)(k0 + r)*N + n] : 0.f;
        }
        __syncthreads();
        #pragma unroll
        for (int kk = 0; kk < 16; kk++) {
            float4 a = *(const float4*)&As[kk][ty << 2];
            float4 b = *(const float4*)&Bs[kk][tx << 2];
            float av[4] = {a.x, a.y, a.z, a.w};
            float bv[4] = {b.x, b.y, b.z, b.w};
            #pragma unroll
            for (int i = 0; i < 4; i++)
                #pragma unroll
                for (int j = 0; j < 4; j++)
                    acc[i][j] = fmaf(av[i], bv[j], acc[i][j]);
        }
        __syncthreads();
    }
    #pragma unroll
    for (int i = 0; i < 4; i++) {
        int row = m0 + (ty << 2) + i;
        #pragma unroll
        for (int j = 0; j < 4; j++) {
            int n = n0 + (tx << 2) + j;
            if (n >= N) continue;
            out[(size_t)row*N + n] = acc[i][j] + bias[n];
        }
    }
}

// ---------------- flash attention, f32, bf16 output ----------------
__global__ __launch_bounds__(256) void attn_kernel(const float* __restrict__ qkv,
                                                   bf16* __restrict__ out)
{
    __shared__ float Qs[64][68];
    __shared__ float KV[64][68];
    __shared__ float S[64][68];
    __shared__ float mrow[64], lrow[64], arow[64];
    int tid = threadIdx.x;
    int tx = tid & 15, ty = tid >> 4;
    int l0 = blockIdx.x << 6;
    int h  = blockIdx.y;
    int b  = blockIdx.z;
    const float* base = qkv + (size_t)b*L_*(3*H_) + h*HD_;
    #pragma unroll
    for (int i = 0; i < 16; i++) {
        int idx = (i << 8) + tid;
        int r = idx >> 6, c = idx & 63;
        Qs[r][c] = base[(size_t)(l0 + r)*(3*H_) + c];
    }
    if (tid < 64) { mrow[tid] = -1e30f; lrow[tid] = 0.f; }
    float o[4][4] = {};
    __syncthreads();
    for (int kt = 0; kt < 16; kt++) {
        int k0 = kt << 6;
        #pragma unroll
        for (int i = 0; i < 16; i++) {
            int idx = (i << 8) + tid;
            int r = idx >> 6, c = idx & 63;
            KV[r][c] = base[(size_t)(k0 + r)*(3*H_) + H_ + c];
        }
        __syncthreads();
        float s[4][4] = {};
        for (int k = 0; k < 64; k += 4) {
            float4 aa[4], bb[4];
            #pragma unroll
            for (int i = 0; i < 4; i++) aa[i] = *(const float4*)&Qs[(ty<<2)+i][k];
            #pragma unroll
            for (int j = 0; j < 4; j++) bb[j] = *(const float4*)&KV[tx + (j<<4)][k];
            #pragma unroll
            for (int i = 0; i < 4; i++)
                #pragma unroll
                for (int j = 0; j < 4; j++) {
                    s[i][j] = fmaf(aa[i].x, bb[j].x, s[i][j]);
                    s[i][j] = fmaf(aa[i].y, bb[j].y, s[i][j]);
                    s[i][j] = fmaf(aa[i].z, bb[j].z, s[i][j]);
                    s[i][j] = fmaf(aa[i].w, bb[j].w, s[i][j]);
                }
        }
        #pragma unroll
        for (int i = 0; i < 4; i++)
            #pragma unroll
            for (int j = 0; j < 4; j++)
                S[(ty<<2)+i][tx + (j<<4)] = s[i][j] * 0.125f;
        __syncthreads();
        if (tid < 64) {
            int r = tid;
            float mx = mrow[r];
            for (int k = 0; k < 64; k++) mx = fmaxf(mx, S[r][(k + r) & 63]);
            arow[r] = __expf(mrow[r] - mx);
            mrow[r] = mx;
        }
        __syncthreads();
        #pragma unroll
        for (int i = 0; i < 4; i++) {
            float mm = mrow[(ty<<2)+i];
            #pragma unroll
            for (int j = 0; j < 4; j++) {
                int cc = tx + (j<<4);
                S[(ty<<2)+i][cc] = __expf(S[(ty<<2)+i][cc] - mm);
            }
        }
        __syncthreads();
        #pragma unroll
        for (int i = 0; i < 16; i++) {
            int idx = (i << 8) + tid;
            int r = idx >> 6, c = idx & 63;
            KV[c][r] = base[(size_t)(k0 + r)*(3*H_) + 2*H_ + c];
        }
        if (tid < 64) {
            int r = tid;
            float sm = 0.f;
            for (int k = 0; k < 64; k++) sm += S[r][(k + r) & 63];
            lrow[r] = lrow[r]*arow[r] + sm;
        }
        __syncthreads();
        #pragma unroll
        for (int i = 0; i < 4; i++) {
            float al = arow[(ty<<2)+i];
            #pragma unroll
            for (int j = 0; j < 4; j++) o[i][j] *= al;
        }
        for (int k = 0; k < 64; k += 4) {
            float4 pp[4], vv[4];
            #pragma unroll
            for (int i = 0; i < 4; i++) pp[i] = *(const float4*)&S[(ty<<2)+i][k];
            #pragma unroll
            for (int j = 0; j < 4; j++) vv[j] = *(const float4*)&KV[tx + (j<<4)][k];
            #pragma unroll
            for (int i = 0; i < 4; i++)
                #pragma unroll
                for (int j = 0; j < 4; j++) {
                    o[i][j] = fmaf(pp[i].x, vv[j].x, o[i][j]);
                    o[i][j] = fmaf(pp[i].y, vv[j].y, o[i][j]);
                    o[i][j] = fmaf(pp[i].z, vv[j].z, o[i][j]);
                    o[i][j] = fmaf(pp[i].w, vv[j].w, o[i][j]);
                }
        }
        __syncthreads();
    }
    #pragma unroll
    for (int i = 0; i < 4; i++) {
        int r = (ty << 2) + i;
        float inv = 1.f / lrow[r];
        #pragma unroll
        for (int j = 0; j < 4; j++)
            out[((size_t)(b*L_ + l0 + r))*H_ + h*HD_ + tx + (j<<4)] = __float2bfloat16(o[i][j] * inv);
    }
}

// ---------------- launcher ----------------
extern "C" void kernel_launch(void* const* d_in, const int* in_sizes, int n_in,
                              void* d_out, int out_size, void* d_ws, size_t ws_size,
                              hipStream_t stream)
{
    (void)in_sizes; (void)n_in; (void)out_size; (void)ws_size;
    const float* x_tokens  = (const float*)d_in[0];
    const int*   Ltgt      = (const int*)d_in[1];
    const int*   tarr      = (const int*)d_in[2];
    const int*   Tp        = (const int*)d_in[3];
    const float* proj_in_w = (const float*)d_in[4];
    const float* proj_in_b = (const float*)d_in[5];
    const float* t_w1 = (const float*)d_in[6];
    const float* t_b1 = (const float*)d_in[7];
    const float* t_w2 = (const float*)d_in[8];
    const float* t_b2 = (const float*)d_in[9];
    const float* l_w1 = (const float*)d_in[10];
    const float* l_b1 = (const float*)d_in[11];
    const float* l_w2 = (const float*)d_in[12];
    const float* l_b2 = (const float*)d_in[13];
    const float* qkv_w   = (const float*)d_in[14];
    const float* qkv_b   = (const float*)d_in[15];
    const float* aproj_w = (const float*)d_in[16];
    const float* aproj_b = (const float*)d_in[17];
    const float* mlp_w1  = (const float*)d_in[18];
    const float* mlp_b1  = (const float*)d_in[19];
    const float* mlp_w2  = (const float*)d_in[20];
    const float* mlp_b2  = (const float*)d_in[21];
    const float* ada_w   = (const float*)d_in[22];
    const float* ada_b   = (const float*)d_in[23];
    const float* fin_ada_w = (const float*)d_in[24];
    const float* fin_ada_b = (const float*)d_in[25];
    const float* fin_w   = (const float*)d_in[26];
    const float* fin_b   = (const float*)d_in[27];
    float* outp = (float*)d_out;

    char* cur = (char*)d_ws;
    auto alloc_f = [&](size_t n) { float* p = (float*)cur; cur += n*sizeof(float); return p; };
    auto alloc_b = [&](size_t n) { bf16* p = (bf16*)cur; cur += ((n*sizeof(bf16) + 15) & ~15ULL); return p; };

    float* x     = alloc_f((size_t)M_*H_);        // residual stream, f32
    float* qkvb  = alloc_f((size_t)M_*3*H_);      // qkv (f32 for rope/attn); reused as f32 ln buf for head
    bf16*  hbuf  = alloc_b((size_t)M_*H_);        // ln out / attn out, bf16
    bf16*  mid   = alloc_b((size_t)M_*MLPD_);     // gelu mid, bf16
    bf16*  wq    = alloc_b((size_t)3*H_*H_);      // per-layer transposed weights
    bf16*  wp    = alloc_b((size_t)H_*H_);
    bf16*  w1t   = alloc_b((size_t)H_*MLPD_);
    bf16*  w2t   = alloc_b((size_t)MLPD_*H_);
    bf16*  xtb   = alloc_b((size_t)M_*DESM_);     // x_tokens bf16
    bf16*  pint  = alloc_b((size_t)DESM_*H_);     // proj_in_w transposed
    float* mods  = alloc_f(B_*6*H_);
    float* cvec  = alloc_f(B_*H_);
    float* csil  = alloc_f(B_*H_);
    float* tfeat = alloc_f(B_*256);
    float* lfeat = alloc_f(B_*128);
    float* thid  = alloc_f(B_*H_);
    float* lhid  = alloc_f(B_*H_);
    float* fmods = alloc_f(B_*2*H_);
    float* ctab  = alloc_f(L_*HD_);
    float* stab  = alloc_f(L_*HD_);

    // conditioning path
    embed_kernel<<<1, 512, 0, stream>>>(tarr, Tp, Ltgt, tfeat, lfeat);
    rope_init_kernel<<<(L_*HD_)/256, 256, 0, stream>>>(ctab, stab);
    small_gemm<<<(B_*H_+255)/256, 256, 0, stream>>>(tfeat, t_w1, t_b1, thid, 256, H_, 1);
    small_gemm<<<(B_*H_+255)/256, 256, 0, stream>>>(lfeat, l_w1, l_b1, lhid, 128, H_, 1);
    small_gemm<<<(B_*H_+255)/256, 256, 0, stream>>>(thid, t_w2, t_b2, cvec, H_, H_, 0);
    small_gemm<<<(B_*H_+255)/256, 256, 0, stream>>>(lhid, l_w2, l_b2, cvec, H_, H_, 2);
    silu_kernel<<<(B_*H_+255)/256, 256, 0, stream>>>(cvec, csil, B_*H_);

    // x = x_tokens @ proj_in_w + b  (bf16 MFMA)
    f2b_kernel<<<((size_t)M_*DESM_+255)/256, 256, 0, stream>>>(x_tokens, xtb, M_*DESM_);
    wtrans_kernel<<<dim3(H_/32, DESM_/32), 256, 0, stream>>>(proj_in_w, pint, DESM_, H_);
    gemm_bf16<0><<<dim3(H_/128, M_/128), 256, 0, stream>>>(xtb, pint, proj_in_b, x,
                                                           M_, H_, DESM_, nullptr, 0, 0);

    for (int l = 0; l < DEPTH_; l++) {
        // per-layer weight convert+transpose (each weight used exactly once)
        wtrans_kernel<<<dim3(3*H_/32, H_/32), 256, 0, stream>>>(qkv_w + (size_t)l*H_*3*H_, wq, H_, 3*H_);
        wtrans_kernel<<<dim3(H_/32, H_/32), 256, 0, stream>>>(aproj_w + (size_t)l*H_*H_, wp, H_, H_);
        wtrans_kernel<<<dim3(MLPD_/32, H_/32), 256, 0, stream>>>(mlp_w1 + (size_t)l*H_*MLPD_, w1t, H_, MLPD_);
        wtrans_kernel<<<dim3(H_/32, MLPD_/32), 256, 0, stream>>>(mlp_w2 + (size_t)l*MLPD_*H_, w2t, MLPD_, H_);

        small_gemm<<<(B_*6*H_+255)/256, 256, 0, stream>>>(csil, ada_w + (size_t)l*H_*6*H_,
                                                          ada_b + (size_t)l*6*H_, mods, H_, 6*H_, 0);
        ln_mod_kernel<true><<<M_, 256, 0, stream>>>(x, hbuf, mods, 6*H_, 0, H_);
        gemm_bf16<0><<<dim3(3*H_/128, M_/128), 256, 0, stream>>>(hbuf, wq, qkv_b + (size_t)l*3*H_,
                                                                 qkvb, M_, 3*H_, H_, nullptr, 0, 0);
        rope_kernel<<<(B_*L_*NH_*32)/256, 256, 0, stream>>>(qkvb, ctab, stab);
        attn_kernel<<<dim3(L_/64, NH_, B_), 256, 0, stream>>>(qkvb, hbuf);
        gemm_bf16<2><<<dim3(H_/128, M_/128), 256, 0, stream>>>(hbuf, wp, aproj_b + (size_t)l*H_,
                                                               x, M_, H_, H_, mods, 6*H_, 2*H_);
        ln_mod_kernel<true><<<M_, 256, 0, stream>>>(x, hbuf, mods, 6*H_, 3*H_, 4*H_);
        gemm_bf16<1><<<dim3(MLPD_/128, M_/128), 256, 0, stream>>>(hbuf, w1t, mlp_b1 + (size_t)l*MLPD_,
                                                                  mid, M_, MLPD_, H_, nullptr, 0, 0);
        gemm_bf16<2><<<dim3(H_/128, M_/128), 256, 0, stream>>>(mid, w2t, mlp_b2 + (size_t)l*H_,
                                                               x, M_, H_, MLPD_, mods, 6*H_, 5*H_);
    }
    // final head (f32; N=26 is tiny)
    small_gemm<<<(B_*2*H_+255)/256, 256, 0, stream>>>(csil, fin_ada_w, fin_ada_b, fmods, H_, 2*H_, 0);
    ln_mod_kernel<false><<<M_, 256, 0, stream>>>(x, qkvb, fmods, 2*H_, 0, H_);
    gemm_kernel<<<dim3(1, M_/64), 256, 0, stream>>>(qkvb, fin_w, fin_b, outp, M_, 26, H_);
}